// Round 7
// baseline (68.815 us; speedup 1.0000x reference)
//
#include <hip/hip_runtime.h>
#include <hip/hip_bf16.h>
#include <stdint.h>

// Problem: B=32, N=4096, D=256, F=256
//   x = relu(A @ W + bias)            A:[B,F] W:[F,N] -> x:[B,N]
//   mask = x > threshold
//   out[b] = stable-compact(raw_input[b] rows where mask), zero-padded to N.
//
// Kernel 1: tiny GEMM -> packed bit-mask bytes [B][512] (read back as u16).
//           (unchanged from R5/R6; ~2us by issue arithmetic, validated
//            absmax=0 — f64 accumulation is load-bearing.)
// Kernel 2: R5's exact best-measured gather (RPB=32, 256 thr, NT load+store)
//           + XCD-chunked bijective block swizzle (T1): each XCD gets a
//           contiguous 512-block span = 4 full batches, concentrating the
//           per-XCD DRAM request stream for row-buffer locality.

#define BB 32
#define NN 4096
#define DD 256
#define FF 256
#define ASTRIDE (FF + 4)   // padded LDS stride
#define RPB 32             // gather: dst rows per block (4 waves x 8)

typedef float f4 __attribute__((ext_vector_type(4)));

// ---------------- Kernel 1: tiny GEMM -> packed masks -----------------------
// Grid 512 blocks x 256 threads; block owns 8 columns x all 32 batches.
// W read exactly once from HBM. f64 accumulation keeps the mask exact vs the
// f32 reference (validated absmax=0 in R2-R6).
__global__ __launch_bounds__(256) void mask_kernel(
    const float* __restrict__ A,      // [B,F]
    const float* __restrict__ W,      // [F,N]
    const float* __restrict__ bias,   // [N]
    const float* __restrict__ thr_p,  // [1]
    uint8_t* __restrict__ bits8)      // [B][512]
{
    __shared__ float a_sh[BB * ASTRIDE];
    __shared__ float wT[8 * ASTRIDE];

    const int t     = threadIdx.x;
    const int chunk = blockIdx.x;          // 0..511
    const int n0    = chunk * 8;

    for (int i = t; i < BB * FF; i += 256) {
        int b = i >> 8, f = i & 255;
        a_sh[b * ASTRIDE + f] = A[i];
    }
    for (int i = t; i < FF * 8; i += 256) {
        int f = i >> 3, c = i & 7;
        wT[c * ASTRIDE + f] = W[(size_t)f * NN + n0 + c];
    }
    __syncthreads();

    const float thr = thr_p[0];
    const int c = t & 7;
    const int b = t >> 3;

    const f4* ap = reinterpret_cast<const f4*>(a_sh + b * ASTRIDE);
    const f4* wp = reinterpret_cast<const f4*>(wT   + c * ASTRIDE);

    double s0 = 0.0, s1 = 0.0, s2 = 0.0, s3 = 0.0;
    #pragma unroll 8
    for (int fs = 0; fs < FF / 4; ++fs) {
        f4 a4 = ap[fs];
        f4 w4 = wp[fs];
        s0 = fma((double)a4.x, (double)w4.x, s0);
        s1 = fma((double)a4.y, (double)w4.y, s1);
        s2 = fma((double)a4.z, (double)w4.z, s2);
        s3 = fma((double)a4.w, (double)w4.w, s3);
    }
    const float v = (float)((s0 + s1) + (s2 + s3)) + bias[n0 + c];
    const int m = (fmaxf(v, 0.f) > thr) ? 1 : 0;

    unsigned long long bal = __ballot(m);
    if (c == 0) {
        const int g = (t & 63) >> 3;
        bits8[b * 512 + chunk] = (uint8_t)((bal >> (8 * g)) & 0xFF);
    }
}

// ---------------- Kernel 2: fused scan + gather (R5 + XCD swizzle) ----------
// 1D grid 4096 blocks x 256 threads. Swizzled wg -> (batch, 32-row window).
// Block scans its batch's 256 u16 chunks (512 B, L2-resident), expands its
// 32-row dst window into LDS, then 4 waves each copy/zero 8 rows.
__global__ __launch_bounds__(256) void gather_kernel(
    const float* __restrict__ raw,     // [B,N,D]
    const uint16_t* __restrict__ bits, // [B][256]
    float* __restrict__ out)           // [B,N,D]
{
    // XCD-chunked bijective swizzle: nwg=4096, NXCD=8, q=512.
    // Default dispatch round-robins consecutive bids across XCDs; this gives
    // XCD k the contiguous block span [512k, 512(k+1)) = batches 4k..4k+3.
    const int bid = blockIdx.x;
    const int wg  = (bid & 7) * 512 + (bid >> 3);
    const int b   = wg >> 7;            // batch   0..31
    const int j0b = (wg & 127) * RPB;   // dst window start

    const int t = threadIdx.x;

    __shared__ int wsum[4];
    __shared__ int cnt_sh;
    __shared__ int order_sh[RPB];

    // --- per-block scan over packed mask (thread t owns chunk t, 16 cols) ---
    unsigned m = bits[b * 256 + t];
    const int s = __popc(m);

    const int lane = t & 63;
    const int wid  = t >> 6;
    int incl = s;
    #pragma unroll
    for (int d = 1; d < 64; d <<= 1) {
        int x = __shfl_up(incl, d, 64);
        if (lane >= d) incl += x;
    }
    if (lane == 63) wsum[wid] = incl;
    __syncthreads();
    if (t == 0) {
        int run = 0;
        #pragma unroll
        for (int i = 0; i < 4; ++i) { int x = wsum[i]; wsum[i] = run; run += x; }
        cnt_sh = run;
    }
    __syncthreads();

    int base = wsum[wid] + (incl - s);  // stable exclusive prefix for chunk t
    if (base < j0b + RPB && base + s > j0b) {
        const int n0 = t * 16;
        while (m) {
            const int pos = __ffs(m) - 1;
            const unsigned rel = (unsigned)(base - j0b);
            if (rel < RPB) order_sh[rel] = n0 + pos;
            ++base;
            if (base >= j0b + RPB) break;
            m &= m - 1;
        }
    }
    __syncthreads();

    // --- gather/zero: wave wid owns rows j0b + wid*8 .. +7 ---
    const int cnt = cnt_sh;
    const f4* rawb = reinterpret_cast<const f4*>(raw) + (size_t)b * NN * (DD / 4);
    f4*       outb = reinterpret_cast<f4*>(out)       + (size_t)b * NN * (DD / 4);
    const int j0 = j0b + wid * 8;

    #pragma unroll
    for (int g = 0; g < 2; ++g) {
        const int r = j0 + g * 4;
        const int rr = r - j0b;
        f4 v0 = {0.f, 0.f, 0.f, 0.f};
        f4 v1 = {0.f, 0.f, 0.f, 0.f};
        f4 v2 = {0.f, 0.f, 0.f, 0.f};
        f4 v3 = {0.f, 0.f, 0.f, 0.f};
        if (r + 0 < cnt) v0 = __builtin_nontemporal_load(&rawb[(size_t)order_sh[rr + 0] * (DD / 4) + lane]);
        if (r + 1 < cnt) v1 = __builtin_nontemporal_load(&rawb[(size_t)order_sh[rr + 1] * (DD / 4) + lane]);
        if (r + 2 < cnt) v2 = __builtin_nontemporal_load(&rawb[(size_t)order_sh[rr + 2] * (DD / 4) + lane]);
        if (r + 3 < cnt) v3 = __builtin_nontemporal_load(&rawb[(size_t)order_sh[rr + 3] * (DD / 4) + lane]);
        __builtin_nontemporal_store(v0, &outb[(size_t)(r + 0) * (DD / 4) + lane]);
        __builtin_nontemporal_store(v1, &outb[(size_t)(r + 1) * (DD / 4) + lane]);
        __builtin_nontemporal_store(v2, &outb[(size_t)(r + 2) * (DD / 4) + lane]);
        __builtin_nontemporal_store(v3, &outb[(size_t)(r + 3) * (DD / 4) + lane]);
    }
}

extern "C" void kernel_launch(void* const* d_in, const int* in_sizes, int n_in,
                              void* d_out, int out_size, void* d_ws, size_t ws_size,
                              hipStream_t stream) {
    const float* raw  = (const float*)d_in[0];   // [B,N,D]
    const float* A    = (const float*)d_in[1];   // [B,F]
    const float* W    = (const float*)d_in[2];   // [F,N]
    const float* bias = (const float*)d_in[3];   // [N]
    const float* thr  = (const float*)d_in[4];   // [1]
    float* out = (float*)d_out;

    uint8_t* bits8 = (uint8_t*)d_ws;             // B*512 = 16 KB

    mask_kernel<<<512, 256, 0, stream>>>(A, W, bias, thr, bits8);
    gather_kernel<<<NN / RPB * BB, 256, 0, stream>>>(
        raw, (const uint16_t*)bits8, out);
}

// Round 8
// 57.145 us; speedup vs baseline: 1.2042x; 1.2042x over previous
//
#include <hip/hip_runtime.h>
#include <hip/hip_bf16.h>
#include <stdint.h>

// Problem: B=32, N=4096, D=256, F=256
//   x = relu(A @ W + bias)            A:[B,F] W:[F,N] -> x:[B,N]
//   mask = x > threshold
//   out[b] = stable-compact(raw_input[b] rows where mask), zero-padded to N.
//
// Kernel 1 (unchanged since R5): tiny GEMM -> packed bit-mask bytes [B][512]
//   (read back as u16). f64 accumulation is load-bearing: validated absmax=0.
// Kernel 2 (R8): DENSE-READ gather. Each block owns 32 SOURCE rows, reads
//   them unconditionally (raw read exactly once, sequential), scatters the
//   selected ones to their contiguous dst run, zero-fills its share of the
//   tail. All streams dense; scan hides under the pre-issued loads.

#define BB 32
#define NN 4096
#define DD 256
#define FF 256
#define ASTRIDE (FF + 4)   // padded LDS stride
#define RPB 32             // source rows per block (2 chunks)
#define NBLK (NN / RPB)    // 128 blocks per batch

typedef float f4 __attribute__((ext_vector_type(4)));

// ---------------- Kernel 1: tiny GEMM -> packed masks -----------------------
__global__ __launch_bounds__(256) void mask_kernel(
    const float* __restrict__ A,      // [B,F]
    const float* __restrict__ W,      // [F,N]
    const float* __restrict__ bias,   // [N]
    const float* __restrict__ thr_p,  // [1]
    uint8_t* __restrict__ bits8)      // [B][512]
{
    __shared__ float a_sh[BB * ASTRIDE];
    __shared__ float wT[8 * ASTRIDE];

    const int t     = threadIdx.x;
    const int chunk = blockIdx.x;          // 0..511
    const int n0    = chunk * 8;

    for (int i = t; i < BB * FF; i += 256) {
        int b = i >> 8, f = i & 255;
        a_sh[b * ASTRIDE + f] = A[i];
    }
    for (int i = t; i < FF * 8; i += 256) {
        int f = i >> 3, c = i & 7;
        wT[c * ASTRIDE + f] = W[(size_t)f * NN + n0 + c];
    }
    __syncthreads();

    const float thr = thr_p[0];
    const int c = t & 7;
    const int b = t >> 3;

    const f4* ap = reinterpret_cast<const f4*>(a_sh + b * ASTRIDE);
    const f4* wp = reinterpret_cast<const f4*>(wT   + c * ASTRIDE);

    double s0 = 0.0, s1 = 0.0, s2 = 0.0, s3 = 0.0;
    #pragma unroll 8
    for (int fs = 0; fs < FF / 4; ++fs) {
        f4 a4 = ap[fs];
        f4 w4 = wp[fs];
        s0 = fma((double)a4.x, (double)w4.x, s0);
        s1 = fma((double)a4.y, (double)w4.y, s1);
        s2 = fma((double)a4.z, (double)w4.z, s2);
        s3 = fma((double)a4.w, (double)w4.w, s3);
    }
    const float v = (float)((s0 + s1) + (s2 + s3)) + bias[n0 + c];
    const int m = (fmaxf(v, 0.f) > thr) ? 1 : 0;

    unsigned long long bal = __ballot(m);
    if (c == 0) {
        const int g = (t & 63) >> 3;
        bits8[b * 512 + chunk] = (uint8_t)((bal >> (8 * g)) & 0xFF);
    }
}

// ---------------- Kernel 2: dense-read scatter + tail zero ------------------
// Grid (NBLK=128, B) x 256 threads (4 waves). Block bx owns source rows
// [bx*32, bx*32+32). Wave wid reads rows wid*8..wid*8+7 of the window
// unconditionally (dense). Scan of the batch's packed mask (512 B,
// L2-resident) gives each selected row's global destination; the block's
// selected rows form a contiguous dst run. Tail [cnt,N) is zero-filled,
// 1/128 share per block. All branches wave-uniform.
__global__ __launch_bounds__(256) void gather_kernel(
    const float* __restrict__ raw,     // [B,N,D]
    const uint16_t* __restrict__ bits, // [B][256]
    float* __restrict__ out)           // [B,N,D]
{
    const int b    = blockIdx.y;
    const int bx   = blockIdx.x;
    const int t    = threadIdx.x;
    const int lane = t & 63;
    const int wid  = t >> 6;

    __shared__ int wsum[4];
    __shared__ int cnt_sh;
    __shared__ int dst_sh[RPB];   // global dst per local source row, -1 if drop

    // --- issue the 8 dense row loads first (addresses independent of scan) --
    const f4* rawb = reinterpret_cast<const f4*>(raw) + (size_t)b * NN * (DD / 4);
    f4*       outb = reinterpret_cast<f4*>(out)       + (size_t)b * NN * (DD / 4);
    const int srow = bx * RPB + wid * 8;

    f4 v0 = __builtin_nontemporal_load(&rawb[(size_t)(srow + 0) * (DD / 4) + lane]);
    f4 v1 = __builtin_nontemporal_load(&rawb[(size_t)(srow + 1) * (DD / 4) + lane]);
    f4 v2 = __builtin_nontemporal_load(&rawb[(size_t)(srow + 2) * (DD / 4) + lane]);
    f4 v3 = __builtin_nontemporal_load(&rawb[(size_t)(srow + 3) * (DD / 4) + lane]);
    f4 v4 = __builtin_nontemporal_load(&rawb[(size_t)(srow + 4) * (DD / 4) + lane]);
    f4 v5 = __builtin_nontemporal_load(&rawb[(size_t)(srow + 5) * (DD / 4) + lane]);
    f4 v6 = __builtin_nontemporal_load(&rawb[(size_t)(srow + 6) * (DD / 4) + lane]);
    f4 v7 = __builtin_nontemporal_load(&rawb[(size_t)(srow + 7) * (DD / 4) + lane]);

    // --- scan over packed mask (thread t owns chunk t, 16 cols) -------------
    if (t < RPB) dst_sh[t] = -1;

    unsigned m = bits[b * 256 + t];
    const int s = __popc(m);

    int incl = s;
    #pragma unroll
    for (int d = 1; d < 64; d <<= 1) {
        int x = __shfl_up(incl, d, 64);
        if (lane >= d) incl += x;
    }
    if (lane == 63) wsum[wid] = incl;
    __syncthreads();
    if (t == 0) {
        int run = 0;
        #pragma unroll
        for (int i = 0; i < 4; ++i) { int x = wsum[i]; wsum[i] = run; run += x; }
        cnt_sh = run;
    }
    __syncthreads();

    // --- expand: the two threads owning this block's chunks fill dst_sh -----
    const int wchunk0 = bx * 2;           // window = chunks wchunk0, wchunk0+1
    if (t == wchunk0 || t == wchunk0 + 1) {
        const int loc0 = (t - wchunk0) * 16;
        int d = wsum[wid] + (incl - s);   // exclusive prefix of chunk t
        unsigned mm = m;
        while (mm) {
            const int pos = __ffs(mm) - 1;
            dst_sh[loc0 + pos] = d++;
            mm &= mm - 1;
        }
    }
    __syncthreads();

    // --- scatter selected rows (dst run contiguous per block) ---------------
    const int r0 = wid * 8;
    const int d0 = dst_sh[r0 + 0];
    const int d1 = dst_sh[r0 + 1];
    const int d2 = dst_sh[r0 + 2];
    const int d3 = dst_sh[r0 + 3];
    const int d4 = dst_sh[r0 + 4];
    const int d5 = dst_sh[r0 + 5];
    const int d6 = dst_sh[r0 + 6];
    const int d7 = dst_sh[r0 + 7];
    if (d0 >= 0) __builtin_nontemporal_store(v0, &outb[(size_t)d0 * (DD / 4) + lane]);
    if (d1 >= 0) __builtin_nontemporal_store(v1, &outb[(size_t)d1 * (DD / 4) + lane]);
    if (d2 >= 0) __builtin_nontemporal_store(v2, &outb[(size_t)d2 * (DD / 4) + lane]);
    if (d3 >= 0) __builtin_nontemporal_store(v3, &outb[(size_t)d3 * (DD / 4) + lane]);
    if (d4 >= 0) __builtin_nontemporal_store(v4, &outb[(size_t)d4 * (DD / 4) + lane]);
    if (d5 >= 0) __builtin_nontemporal_store(v5, &outb[(size_t)d5 * (DD / 4) + lane]);
    if (d6 >= 0) __builtin_nontemporal_store(v6, &outb[(size_t)d6 * (DD / 4) + lane]);
    if (d7 >= 0) __builtin_nontemporal_store(v7, &outb[(size_t)d7 * (DD / 4) + lane]);

    // --- zero tail: block bx zeroes dst rows [z0, z1) of [cnt, N) -----------
    const int cnt = cnt_sh;
    const int zn  = NN - cnt;
    const int z0  = cnt + (int)(((long long)bx * zn) >> 7);
    const int z1  = cnt + (int)(((long long)(bx + 1) * zn) >> 7);
    const f4 zero = {0.f, 0.f, 0.f, 0.f};
    for (int r = z0 + wid; r < z1; r += 4)
        __builtin_nontemporal_store(zero, &outb[(size_t)r * (DD / 4) + lane]);
}

extern "C" void kernel_launch(void* const* d_in, const int* in_sizes, int n_in,
                              void* d_out, int out_size, void* d_ws, size_t ws_size,
                              hipStream_t stream) {
    const float* raw  = (const float*)d_in[0];   // [B,N,D]
    const float* A    = (const float*)d_in[1];   // [B,F]
    const float* W    = (const float*)d_in[2];   // [F,N]
    const float* bias = (const float*)d_in[3];   // [N]
    const float* thr  = (const float*)d_in[4];   // [1]
    float* out = (float*)d_out;

    uint8_t* bits8 = (uint8_t*)d_ws;             // B*512 = 16 KB

    mask_kernel<<<512, 256, 0, stream>>>(A, W, bias, thr, bits8);
    gather_kernel<<<dim3(NBLK, BB), 256, 0, stream>>>(
        raw, (const uint16_t*)bits8, out);
}

// Round 9
// 55.968 us; speedup vs baseline: 1.2295x; 1.0210x over previous
//
#include <hip/hip_runtime.h>
#include <hip/hip_bf16.h>
#include <stdint.h>

// Problem: B=32, N=4096, D=256, F=256
//   x = relu(A @ W + bias)            A:[B,F] W:[F,N] -> x:[B,N]
//   mask = x > threshold
//   out[b] = stable-compact(raw_input[b] rows where mask), zero-padded to N.
//
// Kernel 1 (unchanged since R5): tiny GEMM -> packed bit-mask bytes [B][512]
//   (read back as u16). f64 accumulation is load-bearing: validated absmax=0.
// Kernel 2 (R9): R8's dense-read gather with ONE change: PLAIN stores
//   (scatter + tail) instead of nontemporal. Theory: plain stores let L2
//   write-combine the 134 MB stream into row-local DRAM bursts (the 7.2 TB/s
//   harness fills use plain stores); NT bypassed that. NT loads kept.

#define BB 32
#define NN 4096
#define DD 256
#define FF 256
#define ASTRIDE (FF + 4)   // padded LDS stride
#define RPB 32             // source rows per block (2 chunks)
#define NBLK (NN / RPB)    // 128 blocks per batch

typedef float f4 __attribute__((ext_vector_type(4)));

// ---------------- Kernel 1: tiny GEMM -> packed masks -----------------------
__global__ __launch_bounds__(256) void mask_kernel(
    const float* __restrict__ A,      // [B,F]
    const float* __restrict__ W,      // [F,N]
    const float* __restrict__ bias,   // [N]
    const float* __restrict__ thr_p,  // [1]
    uint8_t* __restrict__ bits8)      // [B][512]
{
    __shared__ float a_sh[BB * ASTRIDE];
    __shared__ float wT[8 * ASTRIDE];

    const int t     = threadIdx.x;
    const int chunk = blockIdx.x;          // 0..511
    const int n0    = chunk * 8;

    for (int i = t; i < BB * FF; i += 256) {
        int b = i >> 8, f = i & 255;
        a_sh[b * ASTRIDE + f] = A[i];
    }
    for (int i = t; i < FF * 8; i += 256) {
        int f = i >> 3, c = i & 7;
        wT[c * ASTRIDE + f] = W[(size_t)f * NN + n0 + c];
    }
    __syncthreads();

    const float thr = thr_p[0];
    const int c = t & 7;
    const int b = t >> 3;

    const f4* ap = reinterpret_cast<const f4*>(a_sh + b * ASTRIDE);
    const f4* wp = reinterpret_cast<const f4*>(wT   + c * ASTRIDE);

    double s0 = 0.0, s1 = 0.0, s2 = 0.0, s3 = 0.0;
    #pragma unroll 8
    for (int fs = 0; fs < FF / 4; ++fs) {
        f4 a4 = ap[fs];
        f4 w4 = wp[fs];
        s0 = fma((double)a4.x, (double)w4.x, s0);
        s1 = fma((double)a4.y, (double)w4.y, s1);
        s2 = fma((double)a4.z, (double)w4.z, s2);
        s3 = fma((double)a4.w, (double)w4.w, s3);
    }
    const float v = (float)((s0 + s1) + (s2 + s3)) + bias[n0 + c];
    const int m = (fmaxf(v, 0.f) > thr) ? 1 : 0;

    unsigned long long bal = __ballot(m);
    if (c == 0) {
        const int g = (t & 63) >> 3;
        bits8[b * 512 + chunk] = (uint8_t)((bal >> (8 * g)) & 0xFF);
    }
}

// ---------------- Kernel 2: dense-read scatter + tail zero (plain stores) ---
// Grid (NBLK=128, B) x 256 threads (4 waves). Block bx owns source rows
// [bx*32, bx*32+32): reads them unconditionally (dense, NT loads), scan of
// the batch's packed mask gives each selected row's destination (contiguous
// run per block), tail [cnt,N) zero-filled 1/128 per block. Plain stores.
__global__ __launch_bounds__(256) void gather_kernel(
    const float* __restrict__ raw,     // [B,N,D]
    const uint16_t* __restrict__ bits, // [B][256]
    float* __restrict__ out)           // [B,N,D]
{
    const int b    = blockIdx.y;
    const int bx   = blockIdx.x;
    const int t    = threadIdx.x;
    const int lane = t & 63;
    const int wid  = t >> 6;

    __shared__ int wsum[4];
    __shared__ int cnt_sh;
    __shared__ int dst_sh[RPB];   // global dst per local source row, -1 if drop

    // --- issue the 8 dense row loads first (addresses independent of scan) --
    const f4* rawb = reinterpret_cast<const f4*>(raw) + (size_t)b * NN * (DD / 4);
    f4*       outb = reinterpret_cast<f4*>(out)       + (size_t)b * NN * (DD / 4);
    const int srow = bx * RPB + wid * 8;

    f4 v0 = __builtin_nontemporal_load(&rawb[(size_t)(srow + 0) * (DD / 4) + lane]);
    f4 v1 = __builtin_nontemporal_load(&rawb[(size_t)(srow + 1) * (DD / 4) + lane]);
    f4 v2 = __builtin_nontemporal_load(&rawb[(size_t)(srow + 2) * (DD / 4) + lane]);
    f4 v3 = __builtin_nontemporal_load(&rawb[(size_t)(srow + 3) * (DD / 4) + lane]);
    f4 v4 = __builtin_nontemporal_load(&rawb[(size_t)(srow + 4) * (DD / 4) + lane]);
    f4 v5 = __builtin_nontemporal_load(&rawb[(size_t)(srow + 5) * (DD / 4) + lane]);
    f4 v6 = __builtin_nontemporal_load(&rawb[(size_t)(srow + 6) * (DD / 4) + lane]);
    f4 v7 = __builtin_nontemporal_load(&rawb[(size_t)(srow + 7) * (DD / 4) + lane]);

    // --- scan over packed mask (thread t owns chunk t, 16 cols) -------------
    if (t < RPB) dst_sh[t] = -1;

    unsigned m = bits[b * 256 + t];
    const int s = __popc(m);

    int incl = s;
    #pragma unroll
    for (int d = 1; d < 64; d <<= 1) {
        int x = __shfl_up(incl, d, 64);
        if (lane >= d) incl += x;
    }
    if (lane == 63) wsum[wid] = incl;
    __syncthreads();
    if (t == 0) {
        int run = 0;
        #pragma unroll
        for (int i = 0; i < 4; ++i) { int x = wsum[i]; wsum[i] = run; run += x; }
        cnt_sh = run;
    }
    __syncthreads();

    // --- expand: the two threads owning this block's chunks fill dst_sh -----
    const int wchunk0 = bx * 2;           // window = chunks wchunk0, wchunk0+1
    if (t == wchunk0 || t == wchunk0 + 1) {
        const int loc0 = (t - wchunk0) * 16;
        int d = wsum[wid] + (incl - s);   // exclusive prefix of chunk t
        unsigned mm = m;
        while (mm) {
            const int pos = __ffs(mm) - 1;
            dst_sh[loc0 + pos] = d++;
            mm &= mm - 1;
        }
    }
    __syncthreads();

    // --- scatter selected rows (dst run contiguous per block), plain stores -
    const int r0 = wid * 8;
    const int d0 = dst_sh[r0 + 0];
    const int d1 = dst_sh[r0 + 1];
    const int d2 = dst_sh[r0 + 2];
    const int d3 = dst_sh[r0 + 3];
    const int d4 = dst_sh[r0 + 4];
    const int d5 = dst_sh[r0 + 5];
    const int d6 = dst_sh[r0 + 6];
    const int d7 = dst_sh[r0 + 7];
    if (d0 >= 0) outb[(size_t)d0 * (DD / 4) + lane] = v0;
    if (d1 >= 0) outb[(size_t)d1 * (DD / 4) + lane] = v1;
    if (d2 >= 0) outb[(size_t)d2 * (DD / 4) + lane] = v2;
    if (d3 >= 0) outb[(size_t)d3 * (DD / 4) + lane] = v3;
    if (d4 >= 0) outb[(size_t)d4 * (DD / 4) + lane] = v4;
    if (d5 >= 0) outb[(size_t)d5 * (DD / 4) + lane] = v5;
    if (d6 >= 0) outb[(size_t)d6 * (DD / 4) + lane] = v6;
    if (d7 >= 0) outb[(size_t)d7 * (DD / 4) + lane] = v7;

    // --- zero tail: block bx zeroes dst rows [z0, z1) of [cnt, N) -----------
    const int cnt = cnt_sh;
    const int zn  = NN - cnt;
    const int z0  = cnt + (int)(((long long)bx * zn) >> 7);
    const int z1  = cnt + (int)(((long long)(bx + 1) * zn) >> 7);
    const f4 zero = {0.f, 0.f, 0.f, 0.f};
    for (int r = z0 + wid; r < z1; r += 4)
        outb[(size_t)r * (DD / 4) + lane] = zero;
}

extern "C" void kernel_launch(void* const* d_in, const int* in_sizes, int n_in,
                              void* d_out, int out_size, void* d_ws, size_t ws_size,
                              hipStream_t stream) {
    const float* raw  = (const float*)d_in[0];   // [B,N,D]
    const float* A    = (const float*)d_in[1];   // [B,F]
    const float* W    = (const float*)d_in[2];   // [F,N]
    const float* bias = (const float*)d_in[3];   // [N]
    const float* thr  = (const float*)d_in[4];   // [1]
    float* out = (float*)d_out;

    uint8_t* bits8 = (uint8_t*)d_ws;             // B*512 = 16 KB

    mask_kernel<<<512, 256, 0, stream>>>(A, W, bias, thr, bits8);
    gather_kernel<<<dim3(NBLK, BB), 256, 0, stream>>>(
        raw, (const uint16_t*)bits8, out);
}

// Round 10
// 55.853 us; speedup vs baseline: 1.2321x; 1.0021x over previous
//
#include <hip/hip_runtime.h>
#include <hip/hip_bf16.h>
#include <stdint.h>

// Problem: B=32, N=4096, D=256, F=256
//   x = relu(A @ W + bias)            A:[B,F] W:[F,N] -> x:[B,N]
//   mask = x > threshold
//   out[b] = stable-compact(raw_input[b] rows where mask), zero-padded to N.
//
// Kernel 1 (unchanged since R5): tiny GEMM -> packed bit-mask bytes [B][512]
//   (read back as u16). f64 accumulation is load-bearing: validated absmax=0.
// Kernel 2 (R10): R9's dense-read gather with the vmcnt serialization fixed:
//   bits[] is loaded FIRST (oldest outstanding load), so the scan's wait is
//   vmcnt(8) and overlaps with the 8 raw-row HBM loads instead of draining
//   them. Also 3 barriers -> 2 (wave prefix computed locally by all threads).

#define BB 32
#define NN 4096
#define DD 256
#define FF 256
#define ASTRIDE (FF + 4)   // padded LDS stride
#define RPB 32             // source rows per block (2 chunks)
#define NBLK (NN / RPB)    // 128 blocks per batch

typedef float f4 __attribute__((ext_vector_type(4)));

// ---------------- Kernel 1: tiny GEMM -> packed masks -----------------------
__global__ __launch_bounds__(256) void mask_kernel(
    const float* __restrict__ A,      // [B,F]
    const float* __restrict__ W,      // [F,N]
    const float* __restrict__ bias,   // [N]
    const float* __restrict__ thr_p,  // [1]
    uint8_t* __restrict__ bits8)      // [B][512]
{
    __shared__ float a_sh[BB * ASTRIDE];
    __shared__ float wT[8 * ASTRIDE];

    const int t     = threadIdx.x;
    const int chunk = blockIdx.x;          // 0..511
    const int n0    = chunk * 8;

    for (int i = t; i < BB * FF; i += 256) {
        int b = i >> 8, f = i & 255;
        a_sh[b * ASTRIDE + f] = A[i];
    }
    for (int i = t; i < FF * 8; i += 256) {
        int f = i >> 3, c = i & 7;
        wT[c * ASTRIDE + f] = W[(size_t)f * NN + n0 + c];
    }
    __syncthreads();

    const float thr = thr_p[0];
    const int c = t & 7;
    const int b = t >> 3;

    const f4* ap = reinterpret_cast<const f4*>(a_sh + b * ASTRIDE);
    const f4* wp = reinterpret_cast<const f4*>(wT   + c * ASTRIDE);

    double s0 = 0.0, s1 = 0.0, s2 = 0.0, s3 = 0.0;
    #pragma unroll 8
    for (int fs = 0; fs < FF / 4; ++fs) {
        f4 a4 = ap[fs];
        f4 w4 = wp[fs];
        s0 = fma((double)a4.x, (double)w4.x, s0);
        s1 = fma((double)a4.y, (double)w4.y, s1);
        s2 = fma((double)a4.z, (double)w4.z, s2);
        s3 = fma((double)a4.w, (double)w4.w, s3);
    }
    const float v = (float)((s0 + s1) + (s2 + s3)) + bias[n0 + c];
    const int m = (fmaxf(v, 0.f) > thr) ? 1 : 0;

    unsigned long long bal = __ballot(m);
    if (c == 0) {
        const int g = (t & 63) >> 3;
        bits8[b * 512 + chunk] = (uint8_t)((bal >> (8 * g)) & 0xFF);
    }
}

// ---------------- Kernel 2: dense-read scatter + tail zero ------------------
// Grid (NBLK=128, B) x 256 threads (4 waves). Block bx owns source rows
// [bx*32, bx*32+32): reads them unconditionally (dense, NT loads). Scan of
// the batch's packed mask gives each selected row's destination (contiguous
// run per block); tail [cnt,N) zero-filled 1/128 per block. Plain stores.
// ORDER MATTERS: bits load is issued before the raw loads so the scan's
// dependency releases at vmcnt(8), overlapping scan with raw-load latency.
__global__ __launch_bounds__(256) void gather_kernel(
    const float* __restrict__ raw,     // [B,N,D]
    const uint16_t* __restrict__ bits, // [B][256]
    float* __restrict__ out)           // [B,N,D]
{
    const int b    = blockIdx.y;
    const int bx   = blockIdx.x;
    const int t    = threadIdx.x;
    const int lane = t & 63;
    const int wid  = t >> 6;

    __shared__ int wsum[4];
    __shared__ int dst_sh[RPB];   // global dst per local source row, -1 if drop

    // --- bits FIRST: oldest outstanding load -> scan waits at vmcnt(8) ------
    const unsigned m = bits[b * 256 + t];   // thread t owns chunk t (16 cols)

    // --- issue the 8 dense row loads (addresses independent of scan) --------
    const f4* rawb = reinterpret_cast<const f4*>(raw) + (size_t)b * NN * (DD / 4);
    f4*       outb = reinterpret_cast<f4*>(out)       + (size_t)b * NN * (DD / 4);
    const int srow = bx * RPB + wid * 8;

    f4 v0 = __builtin_nontemporal_load(&rawb[(size_t)(srow + 0) * (DD / 4) + lane]);
    f4 v1 = __builtin_nontemporal_load(&rawb[(size_t)(srow + 1) * (DD / 4) + lane]);
    f4 v2 = __builtin_nontemporal_load(&rawb[(size_t)(srow + 2) * (DD / 4) + lane]);
    f4 v3 = __builtin_nontemporal_load(&rawb[(size_t)(srow + 3) * (DD / 4) + lane]);
    f4 v4 = __builtin_nontemporal_load(&rawb[(size_t)(srow + 4) * (DD / 4) + lane]);
    f4 v5 = __builtin_nontemporal_load(&rawb[(size_t)(srow + 5) * (DD / 4) + lane]);
    f4 v6 = __builtin_nontemporal_load(&rawb[(size_t)(srow + 6) * (DD / 4) + lane]);
    f4 v7 = __builtin_nontemporal_load(&rawb[(size_t)(srow + 7) * (DD / 4) + lane]);

    if (t < RPB) dst_sh[t] = -1;

    // --- scan over packed mask (overlaps raw-load latency) ------------------
    const int s = __popc(m);
    int incl = s;
    #pragma unroll
    for (int d = 1; d < 64; d <<= 1) {
        int x = __shfl_up(incl, d, 64);
        if (lane >= d) incl += x;
    }
    if (lane == 63) wsum[wid] = incl;
    __syncthreads();

    // every thread computes cnt + its wave's exclusive prefix locally
    const int w0 = wsum[0], w1 = wsum[1], w2 = wsum[2], w3 = wsum[3];
    const int cnt  = w0 + w1 + w2 + w3;
    const int wpre = (wid > 0 ? w0 : 0) + (wid > 1 ? w1 : 0) + (wid > 2 ? w2 : 0);

    // --- expand: the two threads owning this block's chunks fill dst_sh -----
    const int wchunk0 = bx * 2;           // window = chunks wchunk0, wchunk0+1
    if (t == wchunk0 || t == wchunk0 + 1) {
        const int loc0 = (t - wchunk0) * 16;
        int d = wpre + (incl - s);        // exclusive global prefix of chunk t
        unsigned mm = m;
        while (mm) {
            const int pos = __ffs(mm) - 1;
            dst_sh[loc0 + pos] = d++;
            mm &= mm - 1;
        }
    }
    __syncthreads();

    // --- scatter selected rows (dst run contiguous per block), plain stores -
    const int r0 = wid * 8;
    const int d0 = dst_sh[r0 + 0];
    const int d1 = dst_sh[r0 + 1];
    const int d2 = dst_sh[r0 + 2];
    const int d3 = dst_sh[r0 + 3];
    const int d4 = dst_sh[r0 + 4];
    const int d5 = dst_sh[r0 + 5];
    const int d6 = dst_sh[r0 + 6];
    const int d7 = dst_sh[r0 + 7];
    if (d0 >= 0) outb[(size_t)d0 * (DD / 4) + lane] = v0;
    if (d1 >= 0) outb[(size_t)d1 * (DD / 4) + lane] = v1;
    if (d2 >= 0) outb[(size_t)d2 * (DD / 4) + lane] = v2;
    if (d3 >= 0) outb[(size_t)d3 * (DD / 4) + lane] = v3;
    if (d4 >= 0) outb[(size_t)d4 * (DD / 4) + lane] = v4;
    if (d5 >= 0) outb[(size_t)d5 * (DD / 4) + lane] = v5;
    if (d6 >= 0) outb[(size_t)d6 * (DD / 4) + lane] = v6;
    if (d7 >= 0) outb[(size_t)d7 * (DD / 4) + lane] = v7;

    // --- zero tail: block bx zeroes dst rows [z0, z1) of [cnt, N) -----------
    const int zn = NN - cnt;
    const int z0 = cnt + (int)(((long long)bx * zn) >> 7);
    const int z1 = cnt + (int)(((long long)(bx + 1) * zn) >> 7);
    const f4 zero = {0.f, 0.f, 0.f, 0.f};
    for (int r = z0 + wid; r < z1; r += 4)
        outb[(size_t)r * (DD / 4) + lane] = zero;
}

extern "C" void kernel_launch(void* const* d_in, const int* in_sizes, int n_in,
                              void* d_out, int out_size, void* d_ws, size_t ws_size,
                              hipStream_t stream) {
    const float* raw  = (const float*)d_in[0];   // [B,N,D]
    const float* A    = (const float*)d_in[1];   // [B,F]
    const float* W    = (const float*)d_in[2];   // [F,N]
    const float* bias = (const float*)d_in[3];   // [N]
    const float* thr  = (const float*)d_in[4];   // [1]
    float* out = (float*)d_out;

    uint8_t* bits8 = (uint8_t*)d_ws;             // B*512 = 16 KB

    mask_kernel<<<512, 256, 0, stream>>>(A, W, bias, thr, bits8);
    gather_kernel<<<dim3(NBLK, BB), 256, 0, stream>>>(
        raw, (const uint16_t*)bits8, out);
}